// Round 3
// baseline (360.463 us; speedup 1.0000x reference)
//
#include <hip/hip_runtime.h>

// input_feats: [B=8, L=4096, C=2048] fp32, H=W=64
// points_yx  : [B=8, M=4, P=512, 2] fp32 (y, x) in [0,1)
// output     : [B=8, M=4, POOL=64, C=2048] fp32, chunk mean over k=8 points
constexpr int Bc    = 8;
constexpr int Lc    = 4096;
constexpr int Cc    = 2048;
constexpr int Mc    = 4;
constexpr int Pc    = 512;
constexpr int POOLc = 64;
constexpr int Kc    = 8;     // P / POOL
constexpr int Hc    = 64;
constexpr int Wc    = 64;

__device__ __forceinline__ void fma4(float4& acc, float w, const float4 v) {
    acc.x = fmaf(w, v.x, acc.x);
    acc.y = fmaf(w, v.y, acc.y);
    acc.z = fmaf(w, v.z, acc.z);
    acc.w = fmaf(w, v.w, acc.w);
}

__global__ __launch_bounds__(256, 4) void point_sample_pool_kernel(
    const float* __restrict__ feats,   // [B, H*W, C]
    const float* __restrict__ pts,     // [B, M, P, 2]
    float* __restrict__ out)           // [B, M, POOL, C]
{
    const int blk  = blockIdx.x;             // [0, 2*B*M*POOL) = [0, 4096)
    const int row  = blk >> 1;               // output row [0, 2048)
    const int half = blk & 1;                // channel half
    const int o    = row & (POOLc - 1);      // pool bin
    const int bm   = row >> 6;               // b*M + m
    const int b    = bm >> 2;
    const int tid  = threadIdx.x;

    // One float4 slice per thread; wave = contiguous 1 KB.
    const int c = half * (Cc / 2) + tid * 4;

    const float* fb = feats + (size_t)b * Lc * Cc;
    const float* pb = pts + ((size_t)bm * Pc + (size_t)o * Kc) * 2;

    // Hoist all uniform point coords; precompute row offsets + weights.
    int   off00[Kc], off01[Kc], off10[Kc], off11[Kc];
    float w00[Kc], w01[Kc], w10[Kc], w11[Kc];
#pragma unroll
    for (int j = 0; j < Kc; ++j) {
        const float iy = pb[2 * j + 0] * (float)(Hc - 1);
        const float ix = pb[2 * j + 1] * (float)(Wc - 1);
        const float y0f = floorf(iy);
        const float x0f = floorf(ix);
        const float wy = iy - y0f;
        const float wx = ix - x0f;
        int y0 = (int)y0f; y0 = y0 < 0 ? 0 : (y0 > Hc - 1 ? Hc - 1 : y0);
        int x0 = (int)x0f; x0 = x0 < 0 ? 0 : (x0 > Wc - 1 ? Wc - 1 : x0);
        const int y1 = (y0 + 1 > Hc - 1) ? Hc - 1 : y0 + 1;
        const int x1 = (x0 + 1 > Wc - 1) ? Wc - 1 : x0 + 1;
        off00[j] = (y0 * Wc + x0) * Cc;
        off01[j] = (y0 * Wc + x1) * Cc;
        off10[j] = (y1 * Wc + x0) * Cc;
        off11[j] = (y1 * Wc + x1) * Cc;
        w00[j] = (1.f - wx) * (1.f - wy);
        w01[j] = wx * (1.f - wy);
        w10[j] = (1.f - wx) * wy;
        w11[j] = wx * wy;
    }

    float4 acc0 = make_float4(0.f, 0.f, 0.f, 0.f);
    float4 acc1 = make_float4(0.f, 0.f, 0.f, 0.f);

    // Pairwise: 8 independent dwordx4 loads in flight per iteration.
    // unroll 1 keeps register lifetimes bounded (TLP hides latency).
#pragma unroll 1
    for (int j = 0; j < Kc; j += 2) {
        const float4 a00 = *(const float4*)(fb + off00[j] + c);
        const float4 a01 = *(const float4*)(fb + off01[j] + c);
        const float4 a10 = *(const float4*)(fb + off10[j] + c);
        const float4 a11 = *(const float4*)(fb + off11[j] + c);
        const float4 b00 = *(const float4*)(fb + off00[j + 1] + c);
        const float4 b01 = *(const float4*)(fb + off01[j + 1] + c);
        const float4 b10 = *(const float4*)(fb + off10[j + 1] + c);
        const float4 b11 = *(const float4*)(fb + off11[j + 1] + c);

        fma4(acc0, w00[j], a00);
        fma4(acc0, w01[j], a01);
        fma4(acc0, w10[j], a10);
        fma4(acc0, w11[j], a11);
        fma4(acc1, w00[j + 1], b00);
        fma4(acc1, w01[j + 1], b01);
        fma4(acc1, w10[j + 1], b10);
        fma4(acc1, w11[j + 1], b11);
    }

    const float inv_k = 1.0f / (float)Kc;
    float4 r;
    r.x = (acc0.x + acc1.x) * inv_k;
    r.y = (acc0.y + acc1.y) * inv_k;
    r.z = (acc0.z + acc1.z) * inv_k;
    r.w = (acc0.w + acc1.w) * inv_k;

    *(float4*)(out + (size_t)row * Cc + c) = r;
}

extern "C" void kernel_launch(void* const* d_in, const int* in_sizes, int n_in,
                              void* d_out, int out_size, void* d_ws, size_t ws_size,
                              hipStream_t stream) {
    const float* feats = (const float*)d_in[0];
    const float* pts   = (const float*)d_in[1];
    float* out         = (float*)d_out;

    const int grid = 2 * Bc * Mc * POOLc;  // 4096 blocks
    point_sample_pool_kernel<<<grid, 256, 0, stream>>>(feats, pts, out);
}